// Round 20
// baseline (181.349 us; speedup 1.0000x reference)
//
#include <hip/hip_runtime.h>
#include <hip/hip_bf16.h>
#include <math.h>

#define NROWS 32768
#define DD    1024
#define EE    640
#define VV    320
#define BM    64
#define KT    32      // DD/32
#define CTN   40      // EE/16

typedef __attribute__((ext_vector_type(4))) float float4v;
typedef long long i64t;

static __device__ __forceinline__ void gload_lds16(const void* g, void* l) {
    __builtin_amdgcn_global_load_lds(
        (const __attribute__((address_space(1))) unsigned int*)g,
        (__attribute__((address_space(3))) unsigned int*)l, 16, 0, 0);
}

// Pack W [K=1024][N=640] fp32 -> fp8 e4m3 (scaled x16), MFMA fragment layout:
// frag(kt, ct): lane l, elem e  <=  16*W[kt*32 + (l>>4)*8 + e][ct*16 + (l&15)]
__global__ void pack_w8(const float* __restrict__ W, unsigned char* __restrict__ bp)
{
    const int t = threadIdx.x;
    const int tile = blockIdx.x * 4 + (t >> 6);   // 0..1279 = kt*40+ct
    const int lane = t & 63;
    const int kt = tile / CTN, ct = tile % CTN;
    const int k0 = kt * 32 + (lane >> 4) * 8;
    const int col = ct * 16 + (lane & 15);
    float v[8];
    #pragma unroll
    for (int e = 0; e < 8; ++e)
        v[e] = 16.0f * W[(size_t)(k0 + e) * EE + col];
    int lo = 0, hi = 0;
    lo = __builtin_amdgcn_cvt_pk_fp8_f32(v[0], v[1], lo, false);
    lo = __builtin_amdgcn_cvt_pk_fp8_f32(v[2], v[3], lo, true);
    hi = __builtin_amdgcn_cvt_pk_fp8_f32(v[4], v[5], hi, false);
    hi = __builtin_amdgcn_cvt_pk_fp8_f32(v[6], v[7], hi, true);
    int2 pk; pk.x = lo; pk.y = hi;
    *(int2*)(bp + ((size_t)tile * 64 + lane) * 8) = pk;
}

// Fused, barrier-free mainloop: 512 blocks x 512 threads = 2 blocks/CU.
// Wave cg (0..7): all 64 rows (rf 0..3) x cols cg*80..+79. acc[4][5], fp8.
// B: WAVE-PRIVATE 3-slot ring (2.5KB/slot) staged via global_load_lds with
//    exact per-kt counted vmcnt {0,3,7} -> NO block barriers in the K-loop.
// A: 16KB epoch buffer (16 kt), staged once per epoch; epoch-1's x loaded in
//    4-load batches spread through epoch 0 (cvt'd early to 16 held ints);
//    ONE mid-kernel boundary (2 barriers). Epilogue LDS aliases A (dead).
__global__ __launch_bounds__(512, 4) void fused_vq(
    const float* __restrict__ x, const unsigned char* __restrict__ bp,
    const float* __restrict__ bias, const float* __restrict__ cb,
    const float* __restrict__ gum, float* __restrict__ out,
    float* __restrict__ probs_rep)
{
    __shared__ __align__(16) unsigned char POOL[77824];  // 60KB B + 16KB A/epi
    unsigned char* Bpool = POOL;                         // [8 waves][3][2560]
    unsigned char* Achnk = POOL + 61440;                 // [16][2048]

    const int t    = threadIdx.x;
    const int lane = t & 63;
    const int cg   = t >> 6;            // wave id = 80-col group
    const int n0   = blockIdx.x * BM;

    float4v acc[4][5];
    #pragma unroll
    for (int rf = 0; rf < 4; ++rf)
        #pragma unroll
        for (int ct = 0; ct < 5; ++ct)
            acc[rf][ct] = (float4v)0.f;

    // A staging geometry (thread t -> one (row,kq) slot per kt)
    const int r0 = t >> 3, kq0 = t & 7;
    const int abase = (r0 >> 4)*512 + ((r0 & 15) + ((kq0 >> 1) << 4))*8 + ((kq0 & 1) << 2);
    const float* xr = x + (size_t)(n0 + r0) * DD + kq0 * 4;

    unsigned char* Bw = Bpool + cg * 7680;   // this wave's 3 slots
    auto stageBp = [&](int slot, int ktS) {  // 3 uniform ops (96..127 dup'd)
        const unsigned char* src = bp + ((size_t)ktS * CTN + cg * 5) * 512;
        unsigned char* d = Bw + slot * 2560;
        gload_lds16(src + (size_t)lane * 16,        d + lane * 16);
        gload_lds16(src + (size_t)(64 + lane) * 16, d + (64 + lane) * 16);
        const int q2 = (lane < 32) ? 128 + lane : 96 + lane;
        gload_lds16(src + (size_t)q2 * 16, d + q2 * 16);
    };
    auto cvtpk = [&](float4 v) {
        int pk = 0;
        pk = __builtin_amdgcn_cvt_pk_fp8_f32(v.x, v.y, pk, false);
        pk = __builtin_amdgcn_cvt_pk_fp8_f32(v.z, v.w, pk, true);
        return pk;
    };

    // ---- prologue: epoch-0 A (16 loads -> cvt -> ds_write), B(0),B(1) ----
    {
        float4 xa[16];
        #pragma unroll
        for (int j = 0; j < 16; ++j)
            xa[j] = *(const float4*)(xr + j * 32);
        stageBp(0, 0);
        stageBp(1, 1);
        #pragma unroll
        for (int j = 0; j < 16; ++j)
            *(int*)&Achnk[j * 2048 + abase] = cvtpk(xa[j]);   // auto-waits xa
        asm volatile("s_waitcnt vmcnt(3) lgkmcnt(0)" ::: "memory"); // B(0) landed
        __builtin_amdgcn_s_barrier();
        __builtin_amdgcn_sched_barrier(0);
    }

    float4 xb[16];   // epoch-1 x (batches of 4, statically indexed)
    int    pkv[16];  // cvt'd epoch-1 A words

    #pragma unroll
    for (int kt = 0; kt < KT; ++kt) {
        // ---- epoch boundary: write epoch-1 A ----
        if (kt == 16) {
            __builtin_amdgcn_s_barrier();            // epoch-0 A reads done
            __builtin_amdgcn_sched_barrier(0);
            #pragma unroll
            for (int i = 12; i < 16; ++i) pkv[i] = cvtpk(xb[i]);  // batch 3
            #pragma unroll
            for (int j = 0; j < 16; ++j)
                *(int*)&Achnk[j * 2048 + abase] = pkv[j];
            asm volatile("s_waitcnt lgkmcnt(0)" ::: "memory");
            __builtin_amdgcn_s_barrier();
            __builtin_amdgcn_sched_barrier(0);
        }
        // ---- exact counted wait for B(kt) (staged at kt-2) ----
        {
            const bool e0 = (kt < 16);
            const bool b2 = e0 && (kt >= 4) && (((kt - 2) & 3) == 2);   // x-batch at kt-2
            const bool b1 = e0 && (kt >= 3) && (((kt - 1) & 3) == 2);   // x-batch at kt-1
            const bool k16 = (kt == 16);                                 // batch3 @kt14
            const int N = (kt == KT - 1) ? 0 : (kt <= 0 ? 7 : (3 + (b2 || k16 ? 4 : 0) + (b1 ? 4 : 0)));
            if (N == 0)      asm volatile("s_waitcnt vmcnt(0)" ::: "memory");
            else if (N == 3) asm volatile("s_waitcnt vmcnt(3)" ::: "memory");
            else             asm volatile("s_waitcnt vmcnt(7)" ::: "memory");
            __builtin_amdgcn_sched_barrier(0);
        }
        // ---- ds_read A + B frags ----
        i64t af[4];
        #pragma unroll
        for (int rf = 0; rf < 4; ++rf)
            af[rf] = *(const i64t*)&Achnk[(kt & 15) * 2048 + rf * 512 + lane * 8];
        i64t bf[5];
        {
            const unsigned char* bs = Bw + (kt % 3) * 2560;
            #pragma unroll
            for (int ct = 0; ct < 5; ++ct)
                bf[ct] = *(const i64t*)(bs + ct * 512 + lane * 8);
        }
        __builtin_amdgcn_sched_barrier(0);
        // ---- stage B(kt+2); epoch-1 x batches at kt in {2,6,10,14} ----
        if (kt + 2 < KT) stageBp((kt + 2) % 3, kt + 2);
        if (kt < 16 && (kt & 3) == 2) {
            const int b = (kt - 2) >> 2;
            #pragma unroll
            for (int i = 0; i < 4; ++i)
                xb[b * 4 + i] = *(const float4*)(xr + (16 + b * 4 + i) * 32);
        }
        if (kt == 6)  { pkv[0] = cvtpk(xb[0]); pkv[1] = cvtpk(xb[1]); pkv[2] = cvtpk(xb[2]); pkv[3] = cvtpk(xb[3]); }
        if (kt == 10) { pkv[4] = cvtpk(xb[4]); pkv[5] = cvtpk(xb[5]); pkv[6] = cvtpk(xb[6]); pkv[7] = cvtpk(xb[7]); }
        if (kt == 14) { pkv[8] = cvtpk(xb[8]); pkv[9] = cvtpk(xb[9]); pkv[10] = cvtpk(xb[10]); pkv[11] = cvtpk(xb[11]); }
        __builtin_amdgcn_sched_barrier(0);
        // ---- MFMA ----
        #pragma unroll
        for (int ct = 0; ct < 5; ++ct)
            #pragma unroll
            for (int rf = 0; rf < 4; ++rf)
                acc[rf][ct] = __builtin_amdgcn_mfma_f32_16x16x32_fp8_fp8(af[rf], bf[ct], acc[rf][ct], 0, 0, 0);
    }

    __syncthreads();   // all waves done reading A region -> epilogue may alias it

    // ---- epilogue LDS (aliases Achnk region) ----
    float* probs_blk = (float*)(Achnk);                   // 2560 B
    float (*pmax)[BM] = (float(*)[BM])(Achnk + 2560);     // 2048 B
    float (*psum)[BM] = (float(*)[BM])(Achnk + 4608);     // 2048 B
    int   (*pidx)[BM] = (int(*)[BM])(Achnk + 6656);       // 2048 B
    int   (*fidx)[2]  = (int(*)[2])(Achnk + 8704);        // 512 B
    float (*finv)[2]  = (float(*)[2])(Achnk + 9216);      // 512 B

    // un-scale (W was x16) + bias (zeros in this problem; kept faithful)
    {
        float bv[5];
        #pragma unroll
        for (int ct = 0; ct < 5; ++ct) bv[ct] = bias[cg*80 + ct*16 + (lane & 15)];
        #pragma unroll
        for (int rf = 0; rf < 4; ++rf)
            #pragma unroll
            for (int ct = 0; ct < 5; ++ct)
                #pragma unroll
                for (int r = 0; r < 4; ++r)
                    acc[rf][ct][r] = acc[rf][ct][r] * 0.0625f + bv[ct];
    }

    // ---- Phase A: gumbel-argmax partial + clean exp-sum partial ----
    const int g = cg >> 2;                         // 4 waves per group
    const int goff0 = (cg & 3)*80 + (lane & 15);   // col within group
    #pragma unroll
    for (int rf = 0; rf < 4; ++rf) {
        #pragma unroll
        for (int r = 0; r < 4; ++r) {
            const int rowA = rf*16 + ((lane >> 4) << 2) + r;
            const float* grow = gum + ((size_t)(n0 + rowA)*2 + g)*VV + goff0;
            float m1 = -1e30f; int bi = 0; float es = 0.f;
            #pragma unroll
            for (int ct = 0; ct < 5; ++ct) {
                float zv = acc[rf][ct][r];
                float zg = zv + grow[ct*16];
                if (zg > m1) { m1 = zg; bi = goff0 + ct*16; }
                es += __expf(zv);
            }
            #pragma unroll
            for (int off = 1; off < 16; off <<= 1) {
                float om = __shfl_xor(m1, off);
                int   ob = __shfl_xor(bi, off);
                if (om > m1 || (om == m1 && ob < bi)) { m1 = om; bi = ob; }
                es += __shfl_xor(es, off);
            }
            if ((lane & 15) == 0) {
                pmax[cg][rowA] = m1; pidx[cg][rowA] = bi; psum[cg][rowA] = es;
            }
        }
    }
    for (int c = t; c < EE; c += 512) probs_blk[c] = 0.f;
    __syncthreads();

    // ---- Phase B: combine 4 partials per (row,group) ----
    if (t < 128) {
        const int row = t & 63, gg = t >> 6;
        float m1 = -1e30f; int bi = 0x7fffffff; float s = 0.f;
        #pragma unroll
        for (int c = 0; c < 4; ++c) {
            const float om = pmax[gg*4 + c][row];
            const int   ob = pidx[gg*4 + c][row];
            if (om > m1 || (om == m1 && ob < bi)) { m1 = om; bi = ob; }
            s += psum[gg*4 + c][row];
        }
        fidx[row][gg] = bi;
        finv[row][gg] = 1.f / s;
    }
    __syncthreads();

    // ---- Phase C: probs accumulation ----
    float pacc[5];
    #pragma unroll
    for (int ct = 0; ct < 5; ++ct) pacc[ct] = 0.f;
    #pragma unroll
    for (int rf = 0; rf < 4; ++rf) {
        #pragma unroll
        for (int r = 0; r < 4; ++r) {
            const int rowA = rf*16 + ((lane >> 4) << 2) + r;
            const float inv = finv[rowA][g];
            #pragma unroll
            for (int ct = 0; ct < 5; ++ct)
                pacc[ct] += __expf(acc[rf][ct][r]) * inv;
        }
    }
    #pragma unroll
    for (int off = 16; off < 64; off <<= 1)
        #pragma unroll
        for (int ct = 0; ct < 5; ++ct)
            pacc[ct] += __shfl_xor(pacc[ct], off);
    if (lane < 16) {
        #pragma unroll
        for (int ct = 0; ct < 5; ++ct)
            atomicAdd(&probs_blk[cg*80 + ct*16 + lane], pacc[ct]);
    }
    __syncthreads();

    const int rep = blockIdx.x & 7;
    for (int c = t; c < EE; c += 512)
        atomicAdd(&probs_rep[rep*EE + c], probs_blk[c]);

    // ---- output: codebook gather (row-uniform idx, coalesced) ----
    for (int i = t; i < BM*256; i += 512) {
        const int row = i >> 8, f4 = i & 255;
        const int gg  = f4 >> 7;
        const int idx = fidx[row][gg];
        const float4 v = *(const float4*)&cb[((size_t)gg*VV + idx)*512 + (size_t)(f4 & 127)*4];
        *(float4*)&out[(size_t)(n0 + row)*DD + (size_t)f4*4] = v;
    }
}

// perplexity from 8-replica probs accumulator
__global__ void perp8_kernel(const float* __restrict__ probs_rep,
                             float* __restrict__ outp)
{
    __shared__ float s0[4], s1[4];
    int t = threadIdx.x;   // 256
    float p0 = 0.f, p1 = 0.f;
    for (int c = t; c < EE; c += 256) {
        float a = 0.f;
        #pragma unroll
        for (int rp = 0; rp < 8; ++rp) a += probs_rep[rp*EE + c];
        a *= (1.0f / NROWS);
        float v = a * logf(a + 1e-7f);
        if (c < VV) p0 += v; else p1 += v;
    }
    #pragma unroll
    for (int off = 1; off < 64; off <<= 1) {
        p0 += __shfl_xor(p0, off);
        p1 += __shfl_xor(p1, off);
    }
    if ((t & 63) == 0) { s0[t >> 6] = p0; s1[t >> 6] = p1; }
    __syncthreads();
    if (t == 0) {
        float a0 = s0[0] + s0[1] + s0[2] + s0[3];
        float a1 = s1[0] + s1[1] + s1[2] + s1[3];
        outp[0] = 0.5f * (expf(-a0) + expf(-a1));
    }
}

extern "C" void kernel_launch(void* const* d_in, const int* in_sizes, int n_in,
                              void* d_out, int out_size, void* d_ws, size_t ws_size,
                              hipStream_t stream)
{
    const float* x   = (const float*)d_in[0];
    const float* W   = (const float*)d_in[1];
    const float* b   = (const float*)d_in[2];
    const float* cb  = (const float*)d_in[3];
    const float* gum = (const float*)d_in[4];
    float* out = (float*)d_out;

    // ws layout: [bp8 640KB][probs_rep 20KB]
    char* wsp = (char*)d_ws;
    unsigned char* bp = (unsigned char*)wsp;
    const size_t bp_b = (size_t)DD*EE;            // fp8: 1 byte/elem
    float* probs_rep = (float*)(wsp + bp_b);
    const size_t pr_b = 8*EE*sizeof(float);

    hipMemsetAsync(probs_rep, 0, pr_b, stream);
    pack_w8<<<320, 256, 0, stream>>>(W, bp);
    fused_vq<<<NROWS / BM, 512, 0, stream>>>(x, bp, b, cb, gum, out, probs_rep);
    perp8_kernel<<<1, 256, 0, stream>>>(probs_rep, out + (out_size - 1));
}

// Round 21
// 112.456 us; speedup vs baseline: 1.6126x; 1.6126x over previous
//
#include <hip/hip_runtime.h>
#include <hip/hip_bf16.h>
#include <math.h>

#define NROWS 32768
#define DD    1024
#define EE    640
#define VV    320
#define BM    64
#define KT    32      // DD/32
#define CTN   40      // EE/16

typedef __attribute__((ext_vector_type(4))) float float4v;
typedef long long i64t;

static __device__ __forceinline__ void gload_lds16(const void* g, void* l) {
    __builtin_amdgcn_global_load_lds(
        (const __attribute__((address_space(1))) unsigned int*)g,
        (__attribute__((address_space(3))) unsigned int*)l, 16, 0, 0);
}

// Pack W [K=1024][N=640] fp32 -> fp8 e4m3 (scaled x16), MFMA fragment layout:
// frag(kt, ct): lane l, elem e  <=  16*W[kt*32 + (l>>4)*8 + e][ct*16 + (l&15)]
__global__ void pack_w8(const float* __restrict__ W, unsigned char* __restrict__ bp)
{
    const int t = threadIdx.x;
    const int tile = blockIdx.x * 4 + (t >> 6);   // 0..1279 = kt*40+ct
    const int lane = t & 63;
    const int kt = tile / CTN, ct = tile % CTN;
    const int k0 = kt * 32 + (lane >> 4) * 8;
    const int col = ct * 16 + (lane & 15);
    float v[8];
    #pragma unroll
    for (int e = 0; e < 8; ++e)
        v[e] = 16.0f * W[(size_t)(k0 + e) * EE + col];
    int lo = 0, hi = 0;
    lo = __builtin_amdgcn_cvt_pk_fp8_f32(v[0], v[1], lo, false);
    lo = __builtin_amdgcn_cvt_pk_fp8_f32(v[2], v[3], lo, true);
    hi = __builtin_amdgcn_cvt_pk_fp8_f32(v[4], v[5], hi, false);
    hi = __builtin_amdgcn_cvt_pk_fp8_f32(v[6], v[7], hi, true);
    int2 pk; pk.x = lo; pk.y = hi;
    *(int2*)(bp + ((size_t)tile * 64 + lane) * 8) = pk;
}

// Fused: 512 blocks x 512 threads = 2 blocks/CU (LDS ~74KB). Block: 64 rows x
// all 640 cols. Wave cg (0..7): all 64 rows (rf 0..3) x cols cg*80..+79.
// acc[4][5]. fp8 A+B (B pre-scaled x16; epilogue multiplies by 1/16).
// R15 geometry + R7 counted-vmcnt ring: B = 3x20KB LDS ring; each tile's
// 4 uniform VMEM ops/thread (1 x-load + 3 B-gloads) get a 2-iteration window
// before the vmcnt(4) check — staging flies ACROSS barriers instead of
// draining to 0 every kt. [R21 = final: exact revert to R19, 112.5 us]
__global__ __launch_bounds__(512, 4) void fused_vq(
    const float* __restrict__ x, const unsigned char* __restrict__ bp,
    const float* __restrict__ bias, const float* __restrict__ cb,
    const float* __restrict__ gum, float* __restrict__ out,
    float* __restrict__ probs_rep)
{
    __shared__ unsigned char Bs[3][32 * EE];      // 3 x 20 KB ring
    __shared__ unsigned char As[2][BM * 32];      // 2 x 2 KB
    __shared__ float probs_blk[EE];
    __shared__ float pmax[8][BM];
    __shared__ float psum[8][BM];
    __shared__ int   pidx[8][BM];
    __shared__ int   fidx[BM][2];
    __shared__ float finv[BM][2];

    const int t    = threadIdx.x;
    const int lane = t & 63;
    const int cg   = t >> 6;            // wave id = 80-col group
    const int n0   = blockIdx.x * BM;

    float4v acc[4][5];
    #pragma unroll
    for (int rf = 0; rf < 4; ++rf)
        #pragma unroll
        for (int ct = 0; ct < 5; ++ct)
            acc[rf][ct] = (float4v)0.f;

    // A staging: thread t stages one float4 -> 4 fp8: row r0 = t>>3, quad kq0 = t&7
    const int r0 = t >> 3, kq0 = t & 7;
    const int abase = (r0 >> 4)*512 + ((r0 & 15) + ((kq0 >> 1) << 4))*8 + ((kq0 & 1) << 2);
    const float* xr = x + (size_t)(n0 + r0) * DD + kq0 * 4;

    auto writeA = [&](int bb, float4 v) {
        int pk = 0;
        pk = __builtin_amdgcn_cvt_pk_fp8_f32(v.x, v.y, pk, false);
        pk = __builtin_amdgcn_cvt_pk_fp8_f32(v.z, v.w, pk, true);
        *(int*)&As[bb][abase] = pk;
    };
    // B staging: 1280 16B-slots per kt; UNIFORM 3 ops/thread (t>=256 issues a
    // benign duplicate of slots 1024..1279) so vmcnt counts match per wave.
    auto stageB = [&](int bb, int kt) {
        const unsigned char* src = bp + (size_t)kt * (32 * EE);
        gload_lds16(src + (size_t)t * 16,         &Bs[bb][t * 16]);
        gload_lds16(src + (size_t)(t + 512) * 16, &Bs[bb][(t + 512) * 16]);
        const int q2 = (t < 256) ? (t + 1024) : (t + 768);
        gload_lds16(src + (size_t)q2 * 16, &Bs[bb][q2 * 16]);
    };
    auto mfma5 = [&](int slot, const i64t* af) {
        #pragma unroll
        for (int ct = 0; ct < 5; ++ct) {
            i64t bf = *(const i64t*)&Bs[slot][((cg*5 + ct)*64 + lane)*8];
            #pragma unroll
            for (int rf = 0; rf < 4; ++rf)
                acc[rf][ct] = __builtin_amdgcn_mfma_f32_16x16x32_fp8_fp8(af[rf], bf, acc[rf][ct], 0, 0, 0);
        }
    };

    // ---- prologue: tiles 0,1 issued (x first, then stage => 4 ops/tile) ----
    float4 a00 = *(const float4*)(xr);            // x(0)
    stageB(0, 0);
    float4 px1 = *(const float4*)(xr + 32);       // x(1)
    stageB(1, 1);
    float4 px0;
    __builtin_amdgcn_sched_barrier(0);
    writeA(0, a00);                               // auto-waits a00 only
    asm volatile("s_waitcnt vmcnt(4) lgkmcnt(0)" ::: "memory");  // tile0 landed
    __builtin_amdgcn_s_barrier();
    __builtin_amdgcn_sched_barrier(0);

    int bc = 0;   // ring slot of the tile being consumed (= i % 3)
    for (int i = 0; i < KT - 2; i += 2) {
        const int b1 = (bc + 1 > 2) ? 0 : bc + 1;
        const int b2 = (bc + 2 > 2) ? bc - 1 : bc + 2;
        // ---- even iter i: consume slot bc / As[0]; stage tile i+2 -> b2 ----
        {
            px0 = *(const float4*)(xr + (size_t)(i + 2) * 32);   // x(i+2) FIRST
            stageB(b2, i + 2);
            __builtin_amdgcn_sched_barrier(0);
            i64t af[4];
            #pragma unroll
            for (int rf = 0; rf < 4; ++rf)
                af[rf] = *(const i64t*)&As[0][rf*512 + lane*8];
            mfma5(bc, af);
            __builtin_amdgcn_sched_barrier(0);
            writeA(1, px1);                                      // x(i+1)
            asm volatile("s_waitcnt vmcnt(4) lgkmcnt(0)" ::: "memory"); // tile i+1 landed
            __builtin_amdgcn_s_barrier();
            __builtin_amdgcn_sched_barrier(0);
        }
        // ---- odd iter i+1: consume slot b1 / As[1]; stage tile i+3 -> bc ----
        {
            px1 = *(const float4*)(xr + (size_t)(i + 3) * 32);   // x(i+3) FIRST
            stageB(bc, i + 3);
            __builtin_amdgcn_sched_barrier(0);
            i64t af[4];
            #pragma unroll
            for (int rf = 0; rf < 4; ++rf)
                af[rf] = *(const i64t*)&As[1][rf*512 + lane*8];
            mfma5(b1, af);
            __builtin_amdgcn_sched_barrier(0);
            writeA(0, px0);                                      // x(i+2)
            asm volatile("s_waitcnt vmcnt(4) lgkmcnt(0)" ::: "memory"); // tile i+2 landed
            __builtin_amdgcn_s_barrier();
            __builtin_amdgcn_sched_barrier(0);
        }
        bc = b2;
    }
    // ---- tail pair: tiles KT-2 (slot bc, As[0]) and KT-1 (slot bc+1, As[1]) ----
    {
        const int b1 = (bc + 1 > 2) ? 0 : bc + 1;
        i64t af[4];
        #pragma unroll
        for (int rf = 0; rf < 4; ++rf)
            af[rf] = *(const i64t*)&As[0][rf*512 + lane*8];
        mfma5(bc, af);
        __builtin_amdgcn_sched_barrier(0);
        writeA(1, px1);                                          // x(KT-1)
        asm volatile("s_waitcnt vmcnt(0) lgkmcnt(0)" ::: "memory");
        __builtin_amdgcn_s_barrier();
        __builtin_amdgcn_sched_barrier(0);
        #pragma unroll
        for (int rf = 0; rf < 4; ++rf)
            af[rf] = *(const i64t*)&As[1][rf*512 + lane*8];
        mfma5(b1, af);
    }

    // un-scale (W was x16) + bias (zeros in this problem; kept faithful)
    {
        float bv[5];
        #pragma unroll
        for (int ct = 0; ct < 5; ++ct) bv[ct] = bias[cg*80 + ct*16 + (lane & 15)];
        #pragma unroll
        for (int rf = 0; rf < 4; ++rf)
            #pragma unroll
            for (int ct = 0; ct < 5; ++ct)
                #pragma unroll
                for (int r = 0; r < 4; ++r)
                    acc[rf][ct][r] = acc[rf][ct][r] * 0.0625f + bv[ct];
    }

    // ---- Phase A: gumbel-argmax partial + clean exp-sum partial ----
    const int g = cg >> 2;                         // 4 waves per group
    const int goff0 = (cg & 3)*80 + (lane & 15);   // col within group
    #pragma unroll
    for (int rf = 0; rf < 4; ++rf) {
        #pragma unroll
        for (int r = 0; r < 4; ++r) {
            const int rowA = rf*16 + ((lane >> 4) << 2) + r;
            const float* grow = gum + ((size_t)(n0 + rowA)*2 + g)*VV + goff0;
            float m1 = -1e30f; int bi = 0; float es = 0.f;
            #pragma unroll
            for (int ct = 0; ct < 5; ++ct) {
                float zv = acc[rf][ct][r];
                float zg = zv + grow[ct*16];
                if (zg > m1) { m1 = zg; bi = goff0 + ct*16; }
                es += __expf(zv);
            }
            #pragma unroll
            for (int off = 1; off < 16; off <<= 1) {
                float om = __shfl_xor(m1, off);
                int   ob = __shfl_xor(bi, off);
                if (om > m1 || (om == m1 && ob < bi)) { m1 = om; bi = ob; }
                es += __shfl_xor(es, off);
            }
            if ((lane & 15) == 0) {
                pmax[cg][rowA] = m1; pidx[cg][rowA] = bi; psum[cg][rowA] = es;
            }
        }
    }
    for (int c = t; c < EE; c += 512) probs_blk[c] = 0.f;
    __syncthreads();

    // ---- Phase B: combine 4 partials per (row,group) ----
    if (t < 128) {
        const int row = t & 63, gg = t >> 6;
        float m1 = -1e30f; int bi = 0x7fffffff; float s = 0.f;
        #pragma unroll
        for (int c = 0; c < 4; ++c) {
            const float om = pmax[gg*4 + c][row];
            const int   ob = pidx[gg*4 + c][row];
            if (om > m1 || (om == m1 && ob < bi)) { m1 = om; bi = ob; }
            s += psum[gg*4 + c][row];
        }
        fidx[row][gg] = bi;
        finv[row][gg] = 1.f / s;
    }
    __syncthreads();

    // ---- Phase C: probs accumulation ----
    float pacc[5];
    #pragma unroll
    for (int ct = 0; ct < 5; ++ct) pacc[ct] = 0.f;
    #pragma unroll
    for (int rf = 0; rf < 4; ++rf) {
        #pragma unroll
        for (int r = 0; r < 4; ++r) {
            const int rowA = rf*16 + ((lane >> 4) << 2) + r;
            const float inv = finv[rowA][g];
            #pragma unroll
            for (int ct = 0; ct < 5; ++ct)
                pacc[ct] += __expf(acc[rf][ct][r]) * inv;
        }
    }
    #pragma unroll
    for (int off = 16; off < 64; off <<= 1)
        #pragma unroll
        for (int ct = 0; ct < 5; ++ct)
            pacc[ct] += __shfl_xor(pacc[ct], off);
    if (lane < 16) {
        #pragma unroll
        for (int ct = 0; ct < 5; ++ct)
            atomicAdd(&probs_blk[cg*80 + ct*16 + lane], pacc[ct]);
    }
    __syncthreads();

    const int rep = blockIdx.x & 7;
    for (int c = t; c < EE; c += 512)
        atomicAdd(&probs_rep[rep*EE + c], probs_blk[c]);

    // ---- output: codebook gather (row-uniform idx, coalesced) ----
    for (int i = t; i < BM*256; i += 512) {
        const int row = i >> 8, f4 = i & 255;
        const int gg  = f4 >> 7;
        const int idx = fidx[row][gg];
        const float4 v = *(const float4*)&cb[((size_t)gg*VV + idx)*512 + (size_t)(f4 & 127)*4];
        *(float4*)&out[(size_t)(n0 + row)*DD + (size_t)f4*4] = v;
    }
}

// perplexity from 8-replica probs accumulator
__global__ void perp8_kernel(const float* __restrict__ probs_rep,
                             float* __restrict__ outp)
{
    __shared__ float s0[4], s1[4];
    int t = threadIdx.x;   // 256
    float p0 = 0.f, p1 = 0.f;
    for (int c = t; c < EE; c += 256) {
        float a = 0.f;
        #pragma unroll
        for (int rp = 0; rp < 8; ++rp) a += probs_rep[rp*EE + c];
        a *= (1.0f / NROWS);
        float v = a * logf(a + 1e-7f);
        if (c < VV) p0 += v; else p1 += v;
    }
    #pragma unroll
    for (int off = 1; off < 64; off <<= 1) {
        p0 += __shfl_xor(p0, off);
        p1 += __shfl_xor(p1, off);
    }
    if ((t & 63) == 0) { s0[t >> 6] = p0; s1[t >> 6] = p1; }
    __syncthreads();
    if (t == 0) {
        float a0 = s0[0] + s0[1] + s0[2] + s0[3];
        float a1 = s1[0] + s1[1] + s1[2] + s1[3];
        outp[0] = 0.5f * (expf(-a0) + expf(-a1));
    }
}

extern "C" void kernel_launch(void* const* d_in, const int* in_sizes, int n_in,
                              void* d_out, int out_size, void* d_ws, size_t ws_size,
                              hipStream_t stream)
{
    const float* x   = (const float*)d_in[0];
    const float* W   = (const float*)d_in[1];
    const float* b   = (const float*)d_in[2];
    const float* cb  = (const float*)d_in[3];
    const float* gum = (const float*)d_in[4];
    float* out = (float*)d_out;

    // ws layout: [bp8 640KB][probs_rep 20KB]
    char* wsp = (char*)d_ws;
    unsigned char* bp = (unsigned char*)wsp;
    const size_t bp_b = (size_t)DD*EE;            // fp8: 1 byte/elem
    float* probs_rep = (float*)(wsp + bp_b);
    const size_t pr_b = 8*EE*sizeof(float);

    hipMemsetAsync(probs_rep, 0, pr_b, stream);
    pack_w8<<<320, 256, 0, stream>>>(W, bp);
    fused_vq<<<NROWS / BM, 512, 0, stream>>>(x, bp, b, cb, gum, out, probs_rep);
    perp8_kernel<<<1, 256, 0, stream>>>(probs_rep, out + (out_size - 1));
}

// Round 22
// 110.669 us; speedup vs baseline: 1.6387x; 1.0161x over previous
//
#include <hip/hip_runtime.h>
#include <hip/hip_bf16.h>
#include <math.h>

#define NROWS 32768
#define DD    1024
#define EE    640
#define VV    320
#define BM    64
#define KT    32      // DD/32
#define CTN   40      // EE/16

typedef __attribute__((ext_vector_type(4))) float float4v;
typedef long long i64t;

static __device__ __forceinline__ void gload_lds16(const void* g, void* l) {
    __builtin_amdgcn_global_load_lds(
        (const __attribute__((address_space(1))) unsigned int*)g,
        (__attribute__((address_space(3))) unsigned int*)l, 16, 0, 0);
}

// Pack W [K=1024][N=640] fp32 -> fp8 e4m3 (scaled x16), MFMA fragment layout:
// frag(kt, ct): lane l, elem e  <=  16*W[kt*32 + (l>>4)*8 + e][ct*16 + (l&15)]
__global__ void pack_w8(const float* __restrict__ W, unsigned char* __restrict__ bp)
{
    const int t = threadIdx.x;
    const int tile = blockIdx.x * 4 + (t >> 6);   // 0..1279 = kt*40+ct
    const int lane = t & 63;
    const int kt = tile / CTN, ct = tile % CTN;
    const int k0 = kt * 32 + (lane >> 4) * 8;
    const int col = ct * 16 + (lane & 15);
    float v[8];
    #pragma unroll
    for (int e = 0; e < 8; ++e)
        v[e] = 16.0f * W[(size_t)(k0 + e) * EE + col];
    int lo = 0, hi = 0;
    lo = __builtin_amdgcn_cvt_pk_fp8_f32(v[0], v[1], lo, false);
    lo = __builtin_amdgcn_cvt_pk_fp8_f32(v[2], v[3], lo, true);
    hi = __builtin_amdgcn_cvt_pk_fp8_f32(v[4], v[5], hi, false);
    hi = __builtin_amdgcn_cvt_pk_fp8_f32(v[6], v[7], hi, true);
    int2 pk; pk.x = lo; pk.y = hi;
    *(int2*)(bp + ((size_t)tile * 64 + lane) * 8) = pk;
}

// Fused: 512 blocks x 512 threads = 2 blocks/CU (LDS ~74KB). Block: 64 rows x
// all 640 cols. Wave cg (0..7): all 64 rows (rf 0..3) x cols cg*80..+79.
// acc[4][5]. fp8 A+B (B pre-scaled x16; epilogue multiplies by 1/16).
// R19 counted-vmcnt 3-ring + T5 setprio around the MFMA cluster: the two
// co-resident blocks are phase-shifted, so MFMA-phase waves win SIMD issue
// arbitration over the sibling block's load-issuing waves.
__global__ __launch_bounds__(512, 4) void fused_vq(
    const float* __restrict__ x, const unsigned char* __restrict__ bp,
    const float* __restrict__ bias, const float* __restrict__ cb,
    const float* __restrict__ gum, float* __restrict__ out,
    float* __restrict__ probs_rep)
{
    __shared__ unsigned char Bs[3][32 * EE];      // 3 x 20 KB ring
    __shared__ unsigned char As[2][BM * 32];      // 2 x 2 KB
    __shared__ float probs_blk[EE];
    __shared__ float pmax[8][BM];
    __shared__ float psum[8][BM];
    __shared__ int   pidx[8][BM];
    __shared__ int   fidx[BM][2];
    __shared__ float finv[BM][2];

    const int t    = threadIdx.x;
    const int lane = t & 63;
    const int cg   = t >> 6;            // wave id = 80-col group
    const int n0   = blockIdx.x * BM;

    float4v acc[4][5];
    #pragma unroll
    for (int rf = 0; rf < 4; ++rf)
        #pragma unroll
        for (int ct = 0; ct < 5; ++ct)
            acc[rf][ct] = (float4v)0.f;

    // A staging: thread t stages one float4 -> 4 fp8: row r0 = t>>3, quad kq0 = t&7
    const int r0 = t >> 3, kq0 = t & 7;
    const int abase = (r0 >> 4)*512 + ((r0 & 15) + ((kq0 >> 1) << 4))*8 + ((kq0 & 1) << 2);
    const float* xr = x + (size_t)(n0 + r0) * DD + kq0 * 4;

    auto writeA = [&](int bb, float4 v) {
        int pk = 0;
        pk = __builtin_amdgcn_cvt_pk_fp8_f32(v.x, v.y, pk, false);
        pk = __builtin_amdgcn_cvt_pk_fp8_f32(v.z, v.w, pk, true);
        *(int*)&As[bb][abase] = pk;
    };
    // B staging: 1280 16B-slots per kt; UNIFORM 3 ops/thread (t>=256 issues a
    // benign duplicate of slots 1024..1279) so vmcnt counts match per wave.
    auto stageB = [&](int bb, int kt) {
        const unsigned char* src = bp + (size_t)kt * (32 * EE);
        gload_lds16(src + (size_t)t * 16,         &Bs[bb][t * 16]);
        gload_lds16(src + (size_t)(t + 512) * 16, &Bs[bb][(t + 512) * 16]);
        const int q2 = (t < 256) ? (t + 1024) : (t + 768);
        gload_lds16(src + (size_t)q2 * 16, &Bs[bb][q2 * 16]);
    };
    auto mfma5 = [&](int slot, const i64t* af) {
        __builtin_amdgcn_s_setprio(1);            // T5: favor MFMA-phase waves
        #pragma unroll
        for (int ct = 0; ct < 5; ++ct) {
            i64t bf = *(const i64t*)&Bs[slot][((cg*5 + ct)*64 + lane)*8];
            #pragma unroll
            for (int rf = 0; rf < 4; ++rf)
                acc[rf][ct] = __builtin_amdgcn_mfma_f32_16x16x32_fp8_fp8(af[rf], bf, acc[rf][ct], 0, 0, 0);
        }
        __builtin_amdgcn_s_setprio(0);
    };

    // ---- prologue: tiles 0,1 issued (x first, then stage => 4 ops/tile) ----
    float4 a00 = *(const float4*)(xr);            // x(0)
    stageB(0, 0);
    float4 px1 = *(const float4*)(xr + 32);       // x(1)
    stageB(1, 1);
    float4 px0;
    __builtin_amdgcn_sched_barrier(0);
    writeA(0, a00);                               // auto-waits a00 only
    asm volatile("s_waitcnt vmcnt(4) lgkmcnt(0)" ::: "memory");  // tile0 landed
    __builtin_amdgcn_s_barrier();
    __builtin_amdgcn_sched_barrier(0);

    int bc = 0;   // ring slot of the tile being consumed (= i % 3)
    for (int i = 0; i < KT - 2; i += 2) {
        const int b1 = (bc + 1 > 2) ? 0 : bc + 1;
        const int b2 = (bc + 2 > 2) ? bc - 1 : bc + 2;
        // ---- even iter i: consume slot bc / As[0]; stage tile i+2 -> b2 ----
        {
            px0 = *(const float4*)(xr + (size_t)(i + 2) * 32);   // x(i+2) FIRST
            stageB(b2, i + 2);
            __builtin_amdgcn_sched_barrier(0);
            i64t af[4];
            #pragma unroll
            for (int rf = 0; rf < 4; ++rf)
                af[rf] = *(const i64t*)&As[0][rf*512 + lane*8];
            mfma5(bc, af);
            __builtin_amdgcn_sched_barrier(0);
            writeA(1, px1);                                      // x(i+1)
            asm volatile("s_waitcnt vmcnt(4) lgkmcnt(0)" ::: "memory"); // tile i+1 landed
            __builtin_amdgcn_s_barrier();
            __builtin_amdgcn_sched_barrier(0);
        }
        // ---- odd iter i+1: consume slot b1 / As[1]; stage tile i+3 -> bc ----
        {
            px1 = *(const float4*)(xr + (size_t)(i + 3) * 32);   // x(i+3) FIRST
            stageB(bc, i + 3);
            __builtin_amdgcn_sched_barrier(0);
            i64t af[4];
            #pragma unroll
            for (int rf = 0; rf < 4; ++rf)
                af[rf] = *(const i64t*)&As[1][rf*512 + lane*8];
            mfma5(b1, af);
            __builtin_amdgcn_sched_barrier(0);
            writeA(0, px0);                                      // x(i+2)
            asm volatile("s_waitcnt vmcnt(4) lgkmcnt(0)" ::: "memory"); // tile i+2 landed
            __builtin_amdgcn_s_barrier();
            __builtin_amdgcn_sched_barrier(0);
        }
        bc = b2;
    }
    // ---- tail pair: tiles KT-2 (slot bc, As[0]) and KT-1 (slot bc+1, As[1]) ----
    {
        const int b1 = (bc + 1 > 2) ? 0 : bc + 1;
        i64t af[4];
        #pragma unroll
        for (int rf = 0; rf < 4; ++rf)
            af[rf] = *(const i64t*)&As[0][rf*512 + lane*8];
        mfma5(bc, af);
        __builtin_amdgcn_sched_barrier(0);
        writeA(1, px1);                                          // x(KT-1)
        asm volatile("s_waitcnt vmcnt(0) lgkmcnt(0)" ::: "memory");
        __builtin_amdgcn_s_barrier();
        __builtin_amdgcn_sched_barrier(0);
        #pragma unroll
        for (int rf = 0; rf < 4; ++rf)
            af[rf] = *(const i64t*)&As[1][rf*512 + lane*8];
        mfma5(b1, af);
    }

    // un-scale (W was x16) + bias (zeros in this problem; kept faithful)
    {
        float bv[5];
        #pragma unroll
        for (int ct = 0; ct < 5; ++ct) bv[ct] = bias[cg*80 + ct*16 + (lane & 15)];
        #pragma unroll
        for (int rf = 0; rf < 4; ++rf)
            #pragma unroll
            for (int ct = 0; ct < 5; ++ct)
                #pragma unroll
                for (int r = 0; r < 4; ++r)
                    acc[rf][ct][r] = acc[rf][ct][r] * 0.0625f + bv[ct];
    }

    // ---- Phase A: gumbel-argmax partial + clean exp-sum partial ----
    const int g = cg >> 2;                         // 4 waves per group
    const int goff0 = (cg & 3)*80 + (lane & 15);   // col within group
    #pragma unroll
    for (int rf = 0; rf < 4; ++rf) {
        #pragma unroll
        for (int r = 0; r < 4; ++r) {
            const int rowA = rf*16 + ((lane >> 4) << 2) + r;
            const float* grow = gum + ((size_t)(n0 + rowA)*2 + g)*VV + goff0;
            float m1 = -1e30f; int bi = 0; float es = 0.f;
            #pragma unroll
            for (int ct = 0; ct < 5; ++ct) {
                float zv = acc[rf][ct][r];
                float zg = zv + grow[ct*16];
                if (zg > m1) { m1 = zg; bi = goff0 + ct*16; }
                es += __expf(zv);
            }
            #pragma unroll
            for (int off = 1; off < 16; off <<= 1) {
                float om = __shfl_xor(m1, off);
                int   ob = __shfl_xor(bi, off);
                if (om > m1 || (om == m1 && ob < bi)) { m1 = om; bi = ob; }
                es += __shfl_xor(es, off);
            }
            if ((lane & 15) == 0) {
                pmax[cg][rowA] = m1; pidx[cg][rowA] = bi; psum[cg][rowA] = es;
            }
        }
    }
    for (int c = t; c < EE; c += 512) probs_blk[c] = 0.f;
    __syncthreads();

    // ---- Phase B: combine 4 partials per (row,group) ----
    if (t < 128) {
        const int row = t & 63, gg = t >> 6;
        float m1 = -1e30f; int bi = 0x7fffffff; float s = 0.f;
        #pragma unroll
        for (int c = 0; c < 4; ++c) {
            const float om = pmax[gg*4 + c][row];
            const int   ob = pidx[gg*4 + c][row];
            if (om > m1 || (om == m1 && ob < bi)) { m1 = om; bi = ob; }
            s += psum[gg*4 + c][row];
        }
        fidx[row][gg] = bi;
        finv[row][gg] = 1.f / s;
    }
    __syncthreads();

    // ---- Phase C: probs accumulation ----
    float pacc[5];
    #pragma unroll
    for (int ct = 0; ct < 5; ++ct) pacc[ct] = 0.f;
    #pragma unroll
    for (int rf = 0; rf < 4; ++rf) {
        #pragma unroll
        for (int r = 0; r < 4; ++r) {
            const int rowA = rf*16 + ((lane >> 4) << 2) + r;
            const float inv = finv[rowA][g];
            #pragma unroll
            for (int ct = 0; ct < 5; ++ct)
                pacc[ct] += __expf(acc[rf][ct][r]) * inv;
        }
    }
    #pragma unroll
    for (int off = 16; off < 64; off <<= 1)
        #pragma unroll
        for (int ct = 0; ct < 5; ++ct)
            pacc[ct] += __shfl_xor(pacc[ct], off);
    if (lane < 16) {
        #pragma unroll
        for (int ct = 0; ct < 5; ++ct)
            atomicAdd(&probs_blk[cg*80 + ct*16 + lane], pacc[ct]);
    }
    __syncthreads();

    const int rep = blockIdx.x & 7;
    for (int c = t; c < EE; c += 512)
        atomicAdd(&probs_rep[rep*EE + c], probs_blk[c]);

    // ---- output: codebook gather (row-uniform idx, coalesced) ----
    for (int i = t; i < BM*256; i += 512) {
        const int row = i >> 8, f4 = i & 255;
        const int gg  = f4 >> 7;
        const int idx = fidx[row][gg];
        const float4 v = *(const float4*)&cb[((size_t)gg*VV + idx)*512 + (size_t)(f4 & 127)*4];
        *(float4*)&out[(size_t)(n0 + row)*DD + (size_t)f4*4] = v;
    }
}

// perplexity from 8-replica probs accumulator
__global__ void perp8_kernel(const float* __restrict__ probs_rep,
                             float* __restrict__ outp)
{
    __shared__ float s0[4], s1[4];
    int t = threadIdx.x;   // 256
    float p0 = 0.f, p1 = 0.f;
    for (int c = t; c < EE; c += 256) {
        float a = 0.f;
        #pragma unroll
        for (int rp = 0; rp < 8; ++rp) a += probs_rep[rp*EE + c];
        a *= (1.0f / NROWS);
        float v = a * logf(a + 1e-7f);
        if (c < VV) p0 += v; else p1 += v;
    }
    #pragma unroll
    for (int off = 1; off < 64; off <<= 1) {
        p0 += __shfl_xor(p0, off);
        p1 += __shfl_xor(p1, off);
    }
    if ((t & 63) == 0) { s0[t >> 6] = p0; s1[t >> 6] = p1; }
    __syncthreads();
    if (t == 0) {
        float a0 = s0[0] + s0[1] + s0[2] + s0[3];
        float a1 = s1[0] + s1[1] + s1[2] + s1[3];
        outp[0] = 0.5f * (expf(-a0) + expf(-a1));
    }
}

extern "C" void kernel_launch(void* const* d_in, const int* in_sizes, int n_in,
                              void* d_out, int out_size, void* d_ws, size_t ws_size,
                              hipStream_t stream)
{
    const float* x   = (const float*)d_in[0];
    const float* W   = (const float*)d_in[1];
    const float* b   = (const float*)d_in[2];
    const float* cb  = (const float*)d_in[3];
    const float* gum = (const float*)d_in[4];
    float* out = (float*)d_out;

    // ws layout: [bp8 640KB][probs_rep 20KB]
    char* wsp = (char*)d_ws;
    unsigned char* bp = (unsigned char*)wsp;
    const size_t bp_b = (size_t)DD*EE;            // fp8: 1 byte/elem
    float* probs_rep = (float*)(wsp + bp_b);
    const size_t pr_b = 8*EE*sizeof(float);

    hipMemsetAsync(probs_rep, 0, pr_b, stream);
    pack_w8<<<320, 256, 0, stream>>>(W, bp);
    fused_vq<<<NROWS / BM, 512, 0, stream>>>(x, bp, b, cb, gum, out, probs_rep);
    perp8_kernel<<<1, 256, 0, stream>>>(probs_rep, out + (out_size - 1));
}